// Round 1
// baseline (842.835 us; speedup 1.0000x reference)
//
#include <hip/hip_runtime.h>
#include <hip/hip_bf16.h>

#define NB 4096
#define NS 32
#define NI 16
#define NH 32

__device__ __forceinline__ float swap32(float v) {
    return __shfl_xor(v, 32, 64);
}

// Same-wave LDS write->read ordering guard (lgkmcnt drain + compiler fence).
__device__ __forceinline__ void wsync() {
    __builtin_amdgcn_wave_barrier();
    asm volatile("s_waitcnt lgkmcnt(0)" ::: "memory");
    __builtin_amdgcn_wave_barrier();
}

__global__ __launch_bounds__(256, 2) void odernn_kernel(
    const float* __restrict__ x,    // (B,S,I)
    const float* __restrict__ t,    // (B,S)
    const float* __restrict__ gWih, // (96,16)
    const float* __restrict__ gWhh, // (96,32)
    const float* __restrict__ gbih, // (96)
    const float* __restrict__ gbhh, // (96)
    const float* __restrict__ oW1,  // (64,32)
    const float* __restrict__ ob1,  // (64)
    const float* __restrict__ oW2,  // (32,64)
    const float* __restrict__ ob2,  // (32)
    const float* __restrict__ oW3,  // (32,32)
    const float* __restrict__ ob3,  // (32)
    const float* __restrict__ fW1,  // (64,32)
    const float* __restrict__ fb1,  // (64)
    const float* __restrict__ fW2,  // (1,64)
    const float* __restrict__ fb2,  // (1)
    float* __restrict__ outp)       // (B,1)
{
    const int lane = threadIdx.x & 63;
    const int wid  = threadIdx.x >> 6;
    const int b    = blockIdx.x * 4 + wid;
    const int r    = lane & 31;     // row within half-wave
    const int hf   = lane >> 5;     // half index

    __shared__ __align__(16) float buf[4][64];   // per-wave broadcast buffer
    float* bufw = buf[wid];
    const float4* bb = reinterpret_cast<const float4*>(bufw);

    // ---------- ODE MLP weights -> per-lane registers ----------
    // Stage1: 64 outputs (lane j owns row j of W1, 32 wts)
    float w1[32];
    {
        const float4* p = reinterpret_cast<const float4*>(oW1) + lane * 8;
        #pragma unroll
        for (int kk = 0; kk < 8; ++kk) {
            float4 v = p[kk];
            w1[4*kk] = v.x; w1[4*kk+1] = v.y; w1[4*kk+2] = v.z; w1[4*kk+3] = v.w;
        }
    }
    // Stage2: 32 outputs, k split across halves (lane (r,hf) owns W2[r][hf*32..+31])
    float w2[32];
    {
        const float4* p = reinterpret_cast<const float4*>(oW2) + r * 16 + hf * 8;
        #pragma unroll
        for (int kk = 0; kk < 8; ++kk) {
            float4 v = p[kk];
            w2[4*kk] = v.x; w2[4*kk+1] = v.y; w2[4*kk+2] = v.z; w2[4*kk+3] = v.w;
        }
    }
    // Stage3: 32 outputs, k split (lane owns W3[r][hf*16..+15])
    float w3[16];
    {
        const float4* p = reinterpret_cast<const float4*>(oW3) + r * 8 + hf * 4;
        #pragma unroll
        for (int kk = 0; kk < 4; ++kk) {
            float4 v = p[kk];
            w3[4*kk] = v.x; w3[4*kk+1] = v.y; w3[4*kk+2] = v.z; w3[4*kk+3] = v.w;
        }
    }
    const float b1r = ob1[lane];
    const float b2r = ob2[r];
    const float b3r = ob3[r];

    // ---------- GRU weights -> per-lane registers ----------
    // cat = [x(16), h(32)], 48 terms per gate row. r/z gates: 24 terms per half.
    float gr_[24], gz_[24], gni[16], gnh[16];
    #pragma unroll
    for (int kk = 0; kk < 24; ++kk) {
        int c = hf * 24 + kk;
        gr_[kk] = (c < 16) ? gWih[r*16 + c]        : gWhh[r*32 + (c-16)];
        gz_[kk] = (c < 16) ? gWih[(32+r)*16 + c]   : gWhh[(32+r)*32 + (c-16)];
    }
    #pragma unroll
    for (int kk = 0; kk < 16; ++kk) {
        gni[kk] = (hf == 0) ? gWih[(64+r)*16 + kk] : 0.0f;  // zero-weight pad: no divergence
        gnh[kk] = gWhh[(64+r)*32 + hf*16 + kk];
    }
    const float brr = gbih[r]      + gbhh[r];
    const float bzz = gbih[32 + r] + gbhh[32 + r];
    const float bin = gbih[64 + r];
    const float bhn = gbhh[64 + r];

    // ---------- ODE MLP: y (distributed, dup halves) -> k (distributed, dup halves)
    auto ode_f = [&](float yv) -> float {
        if (hf == 0) bufw[r] = yv;
        wsync();
        float a1 = b1r;
        #pragma unroll
        for (int kk = 0; kk < 8; ++kk) {
            float4 c = bb[kk];                     // uniform broadcast read
            a1 = fmaf(w1[4*kk  ], c.x, a1);
            a1 = fmaf(w1[4*kk+1], c.y, a1);
            a1 = fmaf(w1[4*kk+2], c.z, a1);
            a1 = fmaf(w1[4*kk+3], c.w, a1);
        }
        a1 = fmaxf(a1, 0.0f);
        bufw[lane] = a1;                           // h1 distributed over 64 lanes
        wsync();
        float a2 = 0.0f;
        #pragma unroll
        for (int kk = 0; kk < 8; ++kk) {
            float4 c = bb[hf*8 + kk];              // 2 distinct addrs (free 2-way)
            a2 = fmaf(w2[4*kk  ], c.x, a2);
            a2 = fmaf(w2[4*kk+1], c.y, a2);
            a2 = fmaf(w2[4*kk+2], c.z, a2);
            a2 = fmaf(w2[4*kk+3], c.w, a2);
        }
        a2 += swap32(a2);
        a2 = fmaxf(a2 + b2r, 0.0f);
        if (hf == 0) bufw[r] = a2;
        wsync();
        float a3 = 0.0f;
        #pragma unroll
        for (int kk = 0; kk < 4; ++kk) {
            float4 c = bb[hf*4 + kk];
            a3 = fmaf(w3[4*kk  ], c.x, a3);
            a3 = fmaf(w3[4*kk+1], c.y, a3);
            a3 = fmaf(w3[4*kk+2], c.z, a3);
            a3 = fmaf(w3[4*kk+3], c.w, a3);
        }
        a3 += swap32(a3);
        return a3 + b3r;
    };

    // ---------- time loop ----------
    float hv = 0.0f;      // hidden carry h[r] (dup halves)
    float outv = 0.0f;    // GRU output out[r] (dup halves)

    for (int s = 0; s < NS - 1; ++s) {
        // stage cat = [x_t, h] into bufw[0..47]
        const float* xrow = x + ((size_t)b * NS + s) * NI;
        if (hf == 0) {
            bufw[16 + r] = hv;
        } else {
            bufw[r & 15] = xrow[r & 15];
        }
        wsync();

        // r/z gates: 24 FMAs per half each
        float ar = 0.0f, az = 0.0f;
        #pragma unroll
        for (int kk = 0; kk < 6; ++kk) {
            float4 c = bb[hf*6 + kk];
            ar = fmaf(gr_[4*kk  ], c.x, ar); ar = fmaf(gr_[4*kk+1], c.y, ar);
            ar = fmaf(gr_[4*kk+2], c.z, ar); ar = fmaf(gr_[4*kk+3], c.w, ar);
            az = fmaf(gz_[4*kk  ], c.x, az); az = fmaf(gz_[4*kk+1], c.y, az);
            az = fmaf(gz_[4*kk+2], c.z, az); az = fmaf(gz_[4*kk+3], c.w, az);
        }
        // n gate: i_n (x part; hf1 has zero weights) and h_n (h part, k-split)
        float in_ = 0.0f, hn = 0.0f;
        #pragma unroll
        for (int kk = 0; kk < 4; ++kk) {
            float4 c = bb[kk];
            in_ = fmaf(gni[4*kk  ], c.x, in_); in_ = fmaf(gni[4*kk+1], c.y, in_);
            in_ = fmaf(gni[4*kk+2], c.z, in_); in_ = fmaf(gni[4*kk+3], c.w, in_);
        }
        #pragma unroll
        for (int kk = 0; kk < 4; ++kk) {
            float4 c = bb[4 + hf*4 + kk];
            hn = fmaf(gnh[4*kk  ], c.x, hn); hn = fmaf(gnh[4*kk+1], c.y, hn);
            hn = fmaf(gnh[4*kk+2], c.z, hn); hn = fmaf(gnh[4*kk+3], c.w, hn);
        }
        ar += swap32(ar); az += swap32(az); in_ += swap32(in_); hn += swap32(hn);
        ar += brr; az += bzz; in_ += bin; hn += bhn;

        float rg = 1.0f / (1.0f + __expf(-ar));
        float zg = 1.0f / (1.0f + __expf(-az));
        float ng = tanhf(fmaf(rg, hn, in_));
        outv = (1.0f - zg) * ng + zg * hv;

        hv = outv;
        if (s < NS - 2) {   // final step's ODE integration is dead -> skip
            const float t0 = t[(size_t)b * NS + s];
            const float t1 = t[(size_t)b * NS + s + 1];
            const float ddt = (t1 - t0) * 0.25f;   // dt / n_sub, n_sub = 4
            float hi = outv;
            for (int sub = 0; sub < 4; ++sub) {
                float k1 = ode_f(hi);
                float k2 = ode_f(fmaf(ddt, 0.2f * k1, hi));
                float k3 = ode_f(fmaf(ddt, fmaf((float)(9.0/40.0), k2, (float)(3.0/40.0) * k1), hi));
                float k4 = ode_f(fmaf(ddt,
                        fmaf((float)(32.0/9.0), k3,
                        fmaf(-(float)(56.0/15.0), k2, (float)(44.0/45.0) * k1)), hi));
                float k5 = ode_f(fmaf(ddt,
                        fmaf(-(float)(212.0/729.0), k4,
                        fmaf((float)(64448.0/6561.0), k3,
                        fmaf(-(float)(25360.0/2187.0), k2, (float)(19372.0/6561.0) * k1))), hi));
                float k6 = ode_f(fmaf(ddt,
                        fmaf(-(float)(5103.0/18656.0), k5,
                        fmaf((float)(49.0/176.0), k4,
                        fmaf((float)(46732.0/5247.0), k3,
                        fmaf(-(float)(355.0/33.0), k2, (float)(9017.0/3168.0) * k1)))), hi));
                hi = fmaf(ddt,
                        fmaf((float)(11.0/84.0), k6,
                        fmaf(-(float)(2187.0/6784.0), k5,
                        fmaf((float)(125.0/192.0), k4,
                        fmaf((float)(500.0/1113.0), k3, (float)(35.0/384.0) * k1)))), hi);
            }
            hv = hi;
        }
    }

    // ---------- FC head: relu(out @ fW1.T + fb1) @ fW2.T + fb2 ----------
    if (hf == 0) bufw[r] = outv;
    wsync();
    float a = fb1[lane];
    {
        const float4* fw = reinterpret_cast<const float4*>(fW1) + lane * 8;
        #pragma unroll
        for (int kk = 0; kk < 8; ++kk) {
            float4 wv = fw[kk];
            float4 c  = bb[kk];
            a = fmaf(wv.x, c.x, a); a = fmaf(wv.y, c.y, a);
            a = fmaf(wv.z, c.z, a); a = fmaf(wv.w, c.w, a);
        }
    }
    a = fmaxf(a, 0.0f);
    float p = a * fW2[lane];
    #pragma unroll
    for (int m = 1; m < 64; m <<= 1) p += __shfl_xor(p, m, 64);
    if (lane == 0) outp[b] = p + fb2[0];
}

extern "C" void kernel_launch(void* const* d_in, const int* in_sizes, int n_in,
                              void* d_out, int out_size, void* d_ws, size_t ws_size,
                              hipStream_t stream) {
    (void)in_sizes; (void)n_in; (void)d_ws; (void)ws_size; (void)out_size;
    odernn_kernel<<<dim3(NB / 4), dim3(256), 0, stream>>>(
        (const float*)d_in[0],  (const float*)d_in[1],
        (const float*)d_in[2],  (const float*)d_in[3],
        (const float*)d_in[4],  (const float*)d_in[5],
        (const float*)d_in[6],  (const float*)d_in[7],
        (const float*)d_in[8],  (const float*)d_in[9],
        (const float*)d_in[10], (const float*)d_in[11],
        (const float*)d_in[12], (const float*)d_in[13],
        (const float*)d_in[14], (const float*)d_in[15],
        (float*)d_out);
}